// Round 5
// baseline (187.220 us; speedup 1.0000x reference)
//
#include <hip/hip_runtime.h>
#include <stdint.h>

#define Bb 2
#define Ss 2048
#define Dd 1024
#define Hh 8
#define Ee 128
#define KWW 16
#define Mm (Bb*Ss)   // 4096
#define Kk 1024      // K for both GEMMs

typedef unsigned short u16;
typedef __attribute__((ext_vector_type(8))) _Float16 f16x8;  // 8 fp16 (4 VGPRs)
typedef __attribute__((ext_vector_type(4))) float f32x4;

// fp32 -> fp16 (RTN)
__device__ __forceinline__ u16 f2h(float f) {
  union { _Float16 h; u16 u; } v; v.h = (_Float16)f; return v.u;
}
__device__ __forceinline__ float h2f(u16 u) {
  union { u16 u; _Float16 h; } v; v.u = u; return (float)v.h;
}
__device__ __forceinline__ float h2f_lo(uint32_t w) { return h2f((u16)(w & 0xFFFF)); }
__device__ __forceinline__ float h2f_hi(uint32_t w) { return h2f((u16)(w >> 16)); }

// async global->LDS, 16B per lane. LDS dst must be wave-uniform base; HW scatters lane*16B.
__device__ __forceinline__ void gll16(const void* g, void* l) {
  __builtin_amdgcn_global_load_lds((const __attribute__((address_space(1))) void*)g,
                                   (__attribute__((address_space(3))) void*)l, 16, 0, 0);
}

// ---------------- fused prep kernel ----------------
// blocks [0,4096): cast x f32->f16
// blocks [4096,7168): per-head transpose Wq/Wk/Wv [h][D][E] -> wT[z][E][D], z=proj*8+h
// blocks [7168,8192): Wo [h*E][D] -> woT [D][h*E]
__global__ __launch_bounds__(256) void prep(
    const float* __restrict__ x, const float* __restrict__ Wq,
    const float* __restrict__ Wk, const float* __restrict__ Wv,
    const float* __restrict__ Wo,
    u16* __restrict__ xh, u16* __restrict__ wT, u16* __restrict__ woT) {
  const int bid = blockIdx.x;
  const int tid = threadIdx.x;
  if (bid < 4096) {
    int i = (bid * 256 + tid) * 4;
    float4 f = *(const float4*)(x + i);
    uint64_t pk = (uint64_t)f2h(f.x) | ((uint64_t)f2h(f.y) << 16) |
                  ((uint64_t)f2h(f.z) << 32) | ((uint64_t)f2h(f.w) << 48);
    *(uint64_t*)(xh + i) = pk;
    return;
  }
  __shared__ float tile[32][33];  // +1 pad: bank-conflict-free
  const int tx = tid & 31, ty = tid >> 5;  // (32,8) shape
  if (bid < 4096 + 3072) {
    const int idx = bid - 4096;
    const int z = idx >> 7, rem = idx & 127;
    const int h = z & 7;
    const float* W = (z < 8) ? Wq : (z < 16) ? Wk : Wv;
    const float* ib = W + (size_t)h * Dd * Ee;
    u16* ob = wT + (size_t)z * Ee * Kk;
    const int r0 = (rem & 31) * 32, c0 = (rem >> 5) * 32;  // r over D, c over E
    #pragma unroll
    for (int kq = 0; kq < 4; kq++)
      tile[ty + 8*kq][tx] = ib[(size_t)(r0 + ty + 8*kq) * Ee + (c0 + tx)];
    __syncthreads();
    #pragma unroll
    for (int kq = 0; kq < 4; kq++)
      ob[(size_t)(c0 + ty + 8*kq) * Dd + (r0 + tx)] = f2h(tile[tx][ty + 8*kq]);
  } else {
    const int idx = bid - (4096 + 3072);
    const int r0 = (idx & 31) * 32, c0 = (idx >> 5) * 32;  // r over h*E, c over D
    const int R = Hh * Ee, C = Dd;
    #pragma unroll
    for (int kq = 0; kq < 4; kq++)
      tile[ty + 8*kq][tx] = Wo[(size_t)(r0 + ty + 8*kq) * C + (c0 + tx)];
    __syncthreads();
    #pragma unroll
    for (int kq = 0; kq < 4; kq++)
      woT[(size_t)(c0 + ty + 8*kq) * R + (r0 + tx)] = f2h(tile[tx][ty + 8*kq]);
  }
}

// ---------------- GEMM core: MTx128 tile, BK=64, 4 waves, 16x16x32 f16 MFMA ----------------
// A: [M][K] f16 row-major; Bt: [N][K] f16 row-major (B^T form).
// LDS tile rows are 64 elems (128 B) — all rows alias the same banks, so staging
// XOR-swizzles the 16B chunk column by (row&7) via per-lane global source permute
// (LDS dest of global_load_lds is rigid: wave-uniform base + lane*16B).
// Chunk p = row*8 + pc holds A[row][((pc ^ (row&7))*8) .. +7].
template<int MT>   // 128 or 64
__device__ __forceinline__ void gemm_core(
    const u16* __restrict__ A, const u16* __restrict__ Bt,
    u16* As, u16* Bs, f32x4 (&acc)[MT / 32][4]) {
  constexpr int MI = MT / 32;
  const int tid = threadIdx.x;
  const int wave = tid >> 6;
  const int lane = tid & 63;
  // staging: call c, wave w covers rows (c*4+w)*8 .. +7; lane l -> row +(l>>3),
  // chunk col pc = l&7, logical col lc = pc ^ (l>>3)  [(row&7) == (l>>3) here]
  const size_t lnoff = (size_t)(lane >> 3) * Kk + (size_t)(((lane & 7) ^ (lane >> 3)) * 8);

  const int wm = (wave >> 1) * (MT / 2);  // wave 2x2 arrangement
  const int wn = (wave & 1) * 64;
  const int fr = lane & 15;            // A: m-in-16 / B: n-in-16
  const int q  = lane >> 4;            // k quad: holds k = kwin*32 + q*8 .. +7
  const int sw = fr & 7;               // row-swizzle for frag reads

  #pragma unroll
  for (int i = 0; i < MI; i++)
    #pragma unroll
    for (int j = 0; j < 4; j++)
      #pragma unroll
      for (int r = 0; r < 4; r++) acc[i][j][r] = 0.0f;

  for (int kt = 0; kt < Kk; kt += 64) {
    #pragma unroll
    for (int c = 0; c < MI * 2; c++)
      gll16(A + lnoff + (size_t)((c * 4 + wave) * 8) * Kk + kt, As + (c * 4 + wave) * 512);
    #pragma unroll
    for (int c = 0; c < 4; c++)
      gll16(Bt + lnoff + (size_t)((c * 4 + wave) * 8) * Kk + kt, Bs + (c * 4 + wave) * 512);
    __syncthreads();   // drains vmcnt (global_load_lds) before LDS reads
    #pragma unroll
    for (int ks = 0; ks < 2; ks++) {
      const int col = ((ks << 2) | q) ^ sw;   // phys 16B-chunk column
      f16x8 ah[MI], bh[4];
      #pragma unroll
      for (int i = 0; i < MI; i++)
        ah[i] = *(const f16x8*)(As + (wm + i * 16 + fr) * 64 + col * 8);
      #pragma unroll
      for (int j = 0; j < 4; j++)
        bh[j] = *(const f16x8*)(Bs + (wn + j * 16 + fr) * 64 + col * 8);
      #pragma unroll
      for (int i = 0; i < MI; i++)
        #pragma unroll
        for (int j = 0; j < 4; j++)
          acc[i][j] = __builtin_amdgcn_mfma_f32_16x16x32_f16(ah[i], bh[j], acc[i][j], 0, 0, 0);
    }
    __syncthreads();   // ds_reads done before next staging overwrites LDS
  }
}

// C/D layout (measured m89/m91): col = lane&15, row = (lane>>4)*4 + reg

__global__ __launch_bounds__(256) void gemm_qkv(
    const u16* __restrict__ xh, const u16* __restrict__ wT,
    const float* __restrict__ bq, const float* __restrict__ bk, const float* __restrict__ bv,
    u16* __restrict__ q, u16* __restrict__ k, u16* __restrict__ v) {
  __shared__ u16 As[128 * 64];
  __shared__ u16 Bs[128 * 64];
  const int m0 = blockIdx.x * 128;
  const int z = blockIdx.z;            // proj*8 + h
  const int proj = z >> 3, h = z & 7;
  f32x4 acc[4][4];
  gemm_core<128>(xh + (size_t)m0 * Kk, wT + (size_t)z * (Ee * Kk), As, Bs, acc);

  u16* dst = proj == 0 ? q : (proj == 1 ? k : v);
  const float* bias = proj == 0 ? bq : (proj == 1 ? bk : bv);
  const int wave = threadIdx.x >> 6, lane = threadIdx.x & 63;
  const int wm = (wave >> 1) * 64, wn = (wave & 1) * 64;
  const int cn = lane & 15, rq4 = (lane >> 4) * 4;
  #pragma unroll
  for (int j = 0; j < 4; j++) {
    const int e = wn + j * 16 + cn;
    const float bb = bias[h * Ee + e];
    #pragma unroll
    for (int i = 0; i < 4; i++) {
      #pragma unroll
      for (int r = 0; r < 4; r++) {
        const int m = m0 + wm + i * 16 + rq4 + r;     // m = b*S + s
        const int b = m >> 11, s = m & (Ss - 1);
        dst[(((size_t)(b * Hh + h)) * Ss + s) * Ee + e] = f2h(acc[i][j][r] + bb);
      }
    }
  }
}

__global__ __launch_bounds__(256) void gemm_out(
    const u16* __restrict__ attn, const u16* __restrict__ woT,
    const float* __restrict__ bo, float* __restrict__ out) {
  __shared__ u16 As[64 * 64];
  __shared__ u16 Bs[128 * 64];
  const int m0 = blockIdx.x * 64;
  const int n0 = blockIdx.y * 128;
  f32x4 acc[2][4];
  gemm_core<64>(attn + (size_t)m0 * Kk, woT + (size_t)n0 * Kk, As, Bs, acc);
  const int wave = threadIdx.x >> 6, lane = threadIdx.x & 63;
  const int wm = (wave >> 1) * 32, wn = (wave & 1) * 64;
  const int cn = lane & 15, rq4 = (lane >> 4) * 4;
  #pragma unroll
  for (int j = 0; j < 4; j++) {
    const int n = n0 + wn + j * 16 + cn;
    const float bb = bo[n];
    #pragma unroll
    for (int i = 0; i < 2; i++) {
      #pragma unroll
      for (int r = 0; r < 4; r++) {
        const int m = m0 + wm + i * 16 + rq4 + r;
        out[(size_t)m * Dd + n] = acc[i][j][r] + bb;
      }
    }
  }
}

// ---------------- attention: one wave per (b,h,s), fp16 loads, fp32 math ----------------
// Cross-lane plan: reduce-scatter (17 sh) -> per-lane logit j=(lane>>2) -> max/sum
// butterflies (8 sh) -> 1 exp -> allgather weights (15 sh). v rows loaded in J^t
// order so every register index is compile-time.
__global__ __launch_bounds__(256) void attn_kernel(
    const u16* __restrict__ q, const u16* __restrict__ k, const u16* __restrict__ v,
    const float* __restrict__ bk, const float* __restrict__ bv,
    const int* __restrict__ dil, u16* __restrict__ attn) {
  // XCD-contiguous swizzle: XCD i (= blockIdx%8 round-robin) gets a contiguous
  // wid range = 2 whole (b,h) panels -> disjoint ~5MB L2 working set per XCD.
  const int nblk = (Bb * Hh * Ss) / 4;           // 8192
  const int blk = (blockIdx.x & 7) * (nblk / 8) + (blockIdx.x >> 3);
  const int wid = blk * 4 + (threadIdx.x >> 6);
  const int lane = threadIdx.x & 63;
  const int s = wid & (Ss - 1);
  const int bh = wid >> 11;          // b*H + h
  const int h = bh & 7, b = bh >> 3;
  const int d = dil[h];
  const size_t base = (size_t)bh * Ss * Ee;      // u16 elements
  const u16* kp = k + base;
  const u16* vp = v + base;
  const uint32_t qw = *(const uint32_t*)(q + base + (size_t)s * Ee + 2 * lane);
  const float qx = h2f_lo(qw), qy = h2f_hi(qw);
  const float2 bk2 = ((const float2*)(bk + h * Ee))[lane];
  const float2 bv2 = ((const float2*)(bv + h * Ee))[lane];
  const int off = (d * (KWW - 1)) >> 1;
  const int J = (lane >> 2) & 15;

  // ---- logit partials (absolute j; in-window test is wave-uniform) ----
  float logit[KWW];
  #pragma unroll
  for (int j = 0; j < KWW; j++) {
    const int pos = s + d * j - off;
    if (pos >= 0 && pos < Ss) {
      uint32_t kw = *(const uint32_t*)(kp + (size_t)pos * Ee + 2 * lane);
      logit[j] = qx * h2f_lo(kw) + qy * h2f_hi(kw);
    } else {
      logit[j] = qx * bk2.x + qy * bk2.y;  // padded key = bias (NOT masked)
    }
  }
  // ---- v rows in J^t order (per-lane J; clamp+select, no divergent loads) ----
  float vvx[KWW], vvy[KWW];
  #pragma unroll
  for (int t = 0; t < KWW; t++) {
    const int j = J ^ t;
    const int pos = s + d * j - off;
    const int posc = min(max(pos, 0), Ss - 1);
    uint32_t vw = *(const uint32_t*)(vp + (size_t)posc * Ee + 2 * lane);
    const bool ok = (pos >= 0) && (pos < Ss);
    vvx[t] = ok ? h2f_lo(vw) : bv2.x;
    vvy[t] = ok ? h2f_hi(vw) : bv2.y;
  }

  // ---- reduce-scatter: 16 vals over 64 lanes -> lane owns j = (lane>>2) ----
  {
    const bool hi = (lane & 32) != 0;
    #pragma unroll
    for (int j = 0; j < 8; j++) {
      float send = hi ? logit[j] : logit[j + 8];
      float recv = __shfl_xor(send, 32, 64);
      logit[j] = (hi ? logit[j + 8] : logit[j]) + recv;
    }
  }
  {
    const bool hi = (lane & 16) != 0;
    #pragma unroll
    for (int j = 0; j < 4; j++) {
      float send = hi ? logit[j] : logit[j + 4];
      float recv = __shfl_xor(send, 16, 64);
      logit[j] = (hi ? logit[j + 4] : logit[j]) + recv;
    }
  }
  {
    const bool hi = (lane & 8) != 0;
    #pragma unroll
    for (int j = 0; j < 2; j++) {
      float send = hi ? logit[j] : logit[j + 2];
      float recv = __shfl_xor(send, 8, 64);
      logit[j] = (hi ? logit[j + 2] : logit[j]) + recv;
    }
  }
  float own;
  {
    const bool hi = (lane & 4) != 0;
    float send = hi ? logit[0] : logit[1];
    float recv = __shfl_xor(send, 4, 64);
    own = (hi ? logit[1] : logit[0]) + recv;
  }
  own += __shfl_xor(own, 2, 64);
  own += __shfl_xor(own, 1, 64);   // own = full logit for j = J, replicated x4

  // ---- softmax over j (j lives on lane groups; bits 0,1 already uniform) ----
  float mx = own;
  mx = fmaxf(mx, __shfl_xor(mx, 4, 64));
  mx = fmaxf(mx, __shfl_xor(mx, 8, 64));
  mx = fmaxf(mx, __shfl_xor(mx, 16, 64));
  mx = fmaxf(mx, __shfl_xor(mx, 32, 64));
  float w = __expf(own - mx);
  float sum = w;
  sum += __shfl_xor(sum, 4, 64);
  sum += __shfl_xor(sum, 8, 64);
  sum += __shfl_xor(sum, 16, 64);
  sum += __shfl_xor(sum, 32, 64);
  w *= 1.0f / (sum * 11.313708498984760f);  // /Z /sqrt(E), post-softmax quirk

  // ---- allgather: g[t] = w[J^t] ----
  float g[KWW];
  g[0] = w;
  g[1] = __shfl_xor(g[0], 4, 64);
  #pragma unroll
  for (int t = 0; t < 2; t++) g[2 + t] = __shfl_xor(g[t], 8, 64);
  #pragma unroll
  for (int t = 0; t < 4; t++) g[4 + t] = __shfl_xor(g[t], 16, 64);
  #pragma unroll
  for (int t = 0; t < 8; t++) g[8 + t] = __shfl_xor(g[t], 32, 64);

  float ax = 0.f, ay = 0.f;
  #pragma unroll
  for (int t = 0; t < KWW; t++) { ax += g[t] * vvx[t]; ay += g[t] * vvy[t]; }

  // write fp16 attn as A-matrix [b*S+s][h*E+e]
  u16* op = attn + ((size_t)(b * Ss + s)) * (Hh * Ee) + h * Ee + 2 * lane;
  *(uint32_t*)op = (uint32_t)f2h(ax) | ((uint32_t)f2h(ay) << 16);
}

// ---------------- launcher ----------------
extern "C" void kernel_launch(void* const* d_in, const int* in_sizes, int n_in,
                              void* d_out, int out_size, void* d_ws, size_t ws_size,
                              hipStream_t stream) {
  (void)in_sizes; (void)n_in; (void)out_size; (void)ws_size;
  const float* x  = (const float*)d_in[0];
  const float* Wq = (const float*)d_in[1];
  const float* bq = (const float*)d_in[2];
  const float* Wk = (const float*)d_in[3];
  const float* bk = (const float*)d_in[4];
  const float* Wv = (const float*)d_in[5];
  const float* bv = (const float*)d_in[6];
  const float* Wo = (const float*)d_in[7];
  const float* bo = (const float*)d_in[8];
  const int* dil  = (const int*)d_in[9];
  float* out = (float*)d_out;

  char* ws = (char*)d_ws;
  u16* xh  = (u16*)ws;  ws += (size_t)Mm * Kk * 2;             // 8 MB  [m][d] f16
  u16* wT  = (u16*)ws;  ws += (size_t)24 * Ee * Kk * 2;        // 6 MB  [proj*8+h][e][d] f16
  u16* woT = (u16*)ws;  ws += (size_t)Kk * Dd * 2;             // 2 MB  [d][h*E+e] f16
  u16* q = (u16*)ws; ws += (size_t)Bb * Hh * Ss * Ee * 2;      // 8 MB each, f16 [bh][s][e]
  u16* k = (u16*)ws; ws += (size_t)Bb * Hh * Ss * Ee * 2;
  u16* v = (u16*)ws; ws += (size_t)Bb * Hh * Ss * Ee * 2;
  // attn (8 MB f16) aliases xh — dead after gemm_qkv (stream-ordered)
  u16* attn = xh;

  prep<<<8192, 256, 0, stream>>>(x, Wq, Wk, Wv, Wo, xh, wT, woT);
  gemm_qkv<<<dim3(Mm / 128, 1, 24), 256, 0, stream>>>(xh, wT, bq, bk, bv, q, k, v);
  attn_kernel<<<(Bb * Hh * Ss) / 4, 256, 0, stream>>>(q, k, v, bk, bv, dil, attn);
  gemm_out<<<dim3(Mm / 64, Dd / 128), 256, 0, stream>>>(attn, woT, bo, out);
}

// Round 6
// 181.241 us; speedup vs baseline: 1.0330x; 1.0330x over previous
//
#include <hip/hip_runtime.h>
#include <stdint.h>

#define Bb 2
#define Ss 2048
#define Dd 1024
#define Hh 8
#define Ee 128
#define KWW 16
#define Mm (Bb*Ss)   // 4096
#define Kk 1024      // K for both GEMMs

typedef unsigned short u16;
typedef __attribute__((ext_vector_type(8))) _Float16 f16x8;  // 8 fp16 (4 VGPRs)
typedef __attribute__((ext_vector_type(4))) float f32x4;

// fp32 -> fp16 (RTN)
__device__ __forceinline__ u16 f2h(float f) {
  union { _Float16 h; u16 u; } v; v.h = (_Float16)f; return v.u;
}
__device__ __forceinline__ float h2f(u16 u) {
  union { u16 u; _Float16 h; } v; v.u = u; return (float)v.h;
}
__device__ __forceinline__ float h2f_lo(uint32_t w) { return h2f((u16)(w & 0xFFFF)); }
__device__ __forceinline__ float h2f_hi(uint32_t w) { return h2f((u16)(w >> 16)); }

// async global->LDS, 16B per lane. LDS dst must be wave-uniform base; HW scatters lane*16B.
__device__ __forceinline__ void gll16(const void* g, void* l) {
  __builtin_amdgcn_global_load_lds((const __attribute__((address_space(1))) void*)g,
                                   (__attribute__((address_space(3))) void*)l, 16, 0, 0);
}

// ---------------- fused prep kernel ----------------
// blocks [0,4096): cast x f32->f16
// blocks [4096,7168): per-head transpose Wq/Wk/Wv [h][D][E] -> wT[z][E][D], z=proj*8+h
// blocks [7168,8192): Wo [h*E][D] -> woT [D][h*E]
__global__ __launch_bounds__(256) void prep(
    const float* __restrict__ x, const float* __restrict__ Wq,
    const float* __restrict__ Wk, const float* __restrict__ Wv,
    const float* __restrict__ Wo,
    u16* __restrict__ xh, u16* __restrict__ wT, u16* __restrict__ woT) {
  const int bid = blockIdx.x;
  const int tid = threadIdx.x;
  if (bid < 4096) {
    int i = (bid * 256 + tid) * 4;
    float4 f = *(const float4*)(x + i);
    uint64_t pk = (uint64_t)f2h(f.x) | ((uint64_t)f2h(f.y) << 16) |
                  ((uint64_t)f2h(f.z) << 32) | ((uint64_t)f2h(f.w) << 48);
    *(uint64_t*)(xh + i) = pk;
    return;
  }
  __shared__ float tile[32][33];  // +1 pad: bank-conflict-free
  const int tx = tid & 31, ty = tid >> 5;  // (32,8) shape
  if (bid < 4096 + 3072) {
    const int idx = bid - 4096;
    const int z = idx >> 7, rem = idx & 127;
    const int h = z & 7;
    const float* W = (z < 8) ? Wq : (z < 16) ? Wk : Wv;
    const float* ib = W + (size_t)h * Dd * Ee;
    u16* ob = wT + (size_t)z * Ee * Kk;
    const int r0 = (rem & 31) * 32, c0 = (rem >> 5) * 32;  // r over D, c over E
    #pragma unroll
    for (int kq = 0; kq < 4; kq++)
      tile[ty + 8*kq][tx] = ib[(size_t)(r0 + ty + 8*kq) * Ee + (c0 + tx)];
    __syncthreads();
    #pragma unroll
    for (int kq = 0; kq < 4; kq++)
      ob[(size_t)(c0 + ty + 8*kq) * Dd + (r0 + tx)] = f2h(tile[tx][ty + 8*kq]);
  } else {
    const int idx = bid - (4096 + 3072);
    const int r0 = (idx & 31) * 32, c0 = (idx >> 5) * 32;  // r over h*E, c over D
    const int R = Hh * Ee, C = Dd;
    #pragma unroll
    for (int kq = 0; kq < 4; kq++)
      tile[ty + 8*kq][tx] = Wo[(size_t)(r0 + ty + 8*kq) * C + (c0 + tx)];
    __syncthreads();
    #pragma unroll
    for (int kq = 0; kq < 4; kq++)
      woT[(size_t)(c0 + ty + 8*kq) * R + (r0 + tx)] = f2h(tile[tx][ty + 8*kq]);
  }
}

// ---------------- GEMM core: MTx128 tile, BK=64, 4 waves, 16x16x32 f16 MFMA ----------------
// A: [M][K] f16 row-major; Bt: [N][K] f16 row-major (B^T form).
// LDS tile rows are 64 elems (128 B) — all rows alias the same banks, so staging
// XOR-swizzles the 16B chunk column by (row&7) via per-lane global source permute
// (LDS dest of global_load_lds is rigid: wave-uniform base + lane*16B).
// Chunk p = row*8 + pc holds A[row][((pc ^ (row&7))*8) .. +7].
// Staging group g = c*4+wave covers rows g*8..g*8+7; A needs MI groups/wave
// (MT rows total), B needs 4 groups/wave (128 rows). [R4 bug: MI*2 over-staged
// 2x A rows, clobbering Bs (masked by in-order vmcnt retire) — fixed to MI.]
template<int MT>   // 128 or 64
__device__ __forceinline__ void gemm_core(
    const u16* __restrict__ A, const u16* __restrict__ Bt,
    u16* As, u16* Bs, f32x4 (&acc)[MT / 32][4]) {
  constexpr int MI = MT / 32;
  const int tid = threadIdx.x;
  const int wave = tid >> 6;
  const int lane = tid & 63;
  // lane l -> row +(l>>3), chunk col pc = l&7, logical col lc = pc ^ (l>>3)
  const size_t lnoff = (size_t)(lane >> 3) * Kk + (size_t)(((lane & 7) ^ (lane >> 3)) * 8);

  const int wm = (wave >> 1) * (MT / 2);  // wave 2x2 arrangement
  const int wn = (wave & 1) * 64;
  const int fr = lane & 15;            // A: m-in-16 / B: n-in-16
  const int q  = lane >> 4;            // k quad: holds k = kwin*32 + q*8 .. +7
  const int sw = fr & 7;               // row-swizzle for frag reads

  #pragma unroll
  for (int i = 0; i < MI; i++)
    #pragma unroll
    for (int j = 0; j < 4; j++)
      #pragma unroll
      for (int r = 0; r < 4; r++) acc[i][j][r] = 0.0f;

  for (int kt = 0; kt < Kk; kt += 64) {
    #pragma unroll
    for (int c = 0; c < MI; c++)
      gll16(A + lnoff + (size_t)((c * 4 + wave) * 8) * Kk + kt, As + (c * 4 + wave) * 512);
    #pragma unroll
    for (int c = 0; c < 4; c++)
      gll16(Bt + lnoff + (size_t)((c * 4 + wave) * 8) * Kk + kt, Bs + (c * 4 + wave) * 512);
    __syncthreads();   // drains vmcnt (global_load_lds) before LDS reads
    #pragma unroll
    for (int ks = 0; ks < 2; ks++) {
      const int col = ((ks << 2) | q) ^ sw;   // phys 16B-chunk column
      f16x8 ah[MI], bh[4];
      #pragma unroll
      for (int i = 0; i < MI; i++)
        ah[i] = *(const f16x8*)(As + (wm + i * 16 + fr) * 64 + col * 8);
      #pragma unroll
      for (int j = 0; j < 4; j++)
        bh[j] = *(const f16x8*)(Bs + (wn + j * 16 + fr) * 64 + col * 8);
      #pragma unroll
      for (int i = 0; i < MI; i++)
        #pragma unroll
        for (int j = 0; j < 4; j++)
          acc[i][j] = __builtin_amdgcn_mfma_f32_16x16x32_f16(ah[i], bh[j], acc[i][j], 0, 0, 0);
    }
    __syncthreads();   // ds_reads done before next staging overwrites LDS
  }
}

// C/D layout (measured m89/m91): col = lane&15, row = (lane>>4)*4 + reg

__global__ __launch_bounds__(256) void gemm_qkv(
    const u16* __restrict__ xh, const u16* __restrict__ wT,
    const float* __restrict__ bq, const float* __restrict__ bk, const float* __restrict__ bv,
    u16* __restrict__ q, u16* __restrict__ k, u16* __restrict__ v) {
  __shared__ u16 As[128 * 64];
  __shared__ u16 Bs[128 * 64];
  const int m0 = blockIdx.x * 128;
  const int z = blockIdx.z;            // proj*8 + h
  const int proj = z >> 3, h = z & 7;
  f32x4 acc[4][4];
  gemm_core<128>(xh + (size_t)m0 * Kk, wT + (size_t)z * (Ee * Kk), As, Bs, acc);

  u16* dst = proj == 0 ? q : (proj == 1 ? k : v);
  const float* bias = proj == 0 ? bq : (proj == 1 ? bk : bv);
  const int wave = threadIdx.x >> 6, lane = threadIdx.x & 63;
  const int wm = (wave >> 1) * 64, wn = (wave & 1) * 64;
  const int cn = lane & 15, rq4 = (lane >> 4) * 4;
  #pragma unroll
  for (int j = 0; j < 4; j++) {
    const int e = wn + j * 16 + cn;
    const float bb = bias[h * Ee + e];
    #pragma unroll
    for (int i = 0; i < 4; i++) {
      #pragma unroll
      for (int r = 0; r < 4; r++) {
        const int m = m0 + wm + i * 16 + rq4 + r;     // m = b*S + s
        const int b = m >> 11, s = m & (Ss - 1);
        dst[(((size_t)(b * Hh + h)) * Ss + s) * Ee + e] = f2h(acc[i][j][r] + bb);
      }
    }
  }
}

__global__ __launch_bounds__(256) void gemm_out(
    const u16* __restrict__ attn, const u16* __restrict__ woT,
    const float* __restrict__ bo, float* __restrict__ out) {
  __shared__ u16 As[64 * 64];
  __shared__ u16 Bs[128 * 64];
  const int m0 = blockIdx.x * 64;
  const int n0 = blockIdx.y * 128;
  f32x4 acc[2][4];
  gemm_core<64>(attn + (size_t)m0 * Kk, woT + (size_t)n0 * Kk, As, Bs, acc);
  const int wave = threadIdx.x >> 6, lane = threadIdx.x & 63;
  const int wm = (wave >> 1) * 32, wn = (wave & 1) * 64;
  const int cn = lane & 15, rq4 = (lane >> 4) * 4;
  #pragma unroll
  for (int j = 0; j < 4; j++) {
    const int n = n0 + wn + j * 16 + cn;
    const float bb = bo[n];
    #pragma unroll
    for (int i = 0; i < 2; i++) {
      #pragma unroll
      for (int r = 0; r < 4; r++) {
        const int m = m0 + wm + i * 16 + rq4 + r;
        out[(size_t)m * Dd + n] = acc[i][j][r] + bb;
      }
    }
  }
}

// ---------------- attention: one wave per (b,h,s), fp16 loads, fp32 math ----------------
// Cross-lane plan: reduce-scatter (17 sh) -> per-lane logit j=(lane>>2) -> max/sum
// butterflies (8 sh) -> 1 exp -> allgather weights (15 sh). v rows loaded in J^t
// order so every register index is compile-time.
__global__ __launch_bounds__(256) void attn_kernel(
    const u16* __restrict__ q, const u16* __restrict__ k, const u16* __restrict__ v,
    const float* __restrict__ bk, const float* __restrict__ bv,
    const int* __restrict__ dil, u16* __restrict__ attn) {
  // XCD-contiguous swizzle: XCD i (= blockIdx%8 round-robin) gets a contiguous
  // wid range = 2 whole (b,h) panels -> disjoint ~5MB L2 working set per XCD.
  const int nblk = (Bb * Hh * Ss) / 4;           // 8192
  const int blk = (blockIdx.x & 7) * (nblk / 8) + (blockIdx.x >> 3);
  const int wid = blk * 4 + (threadIdx.x >> 6);
  const int lane = threadIdx.x & 63;
  const int s = wid & (Ss - 1);
  const int bh = wid >> 11;          // b*H + h
  const int h = bh & 7, b = bh >> 3;
  const int d = dil[h];
  const size_t base = (size_t)bh * Ss * Ee;      // u16 elements
  const u16* kp = k + base;
  const u16* vp = v + base;
  const uint32_t qw = *(const uint32_t*)(q + base + (size_t)s * Ee + 2 * lane);
  const float qx = h2f_lo(qw), qy = h2f_hi(qw);
  const float2 bk2 = ((const float2*)(bk + h * Ee))[lane];
  const float2 bv2 = ((const float2*)(bv + h * Ee))[lane];
  const int off = (d * (KWW - 1)) >> 1;
  const int J = (lane >> 2) & 15;

  // ---- logit partials (absolute j; in-window test is wave-uniform) ----
  float logit[KWW];
  #pragma unroll
  for (int j = 0; j < KWW; j++) {
    const int pos = s + d * j - off;
    if (pos >= 0 && pos < Ss) {
      uint32_t kw = *(const uint32_t*)(kp + (size_t)pos * Ee + 2 * lane);
      logit[j] = qx * h2f_lo(kw) + qy * h2f_hi(kw);
    } else {
      logit[j] = qx * bk2.x + qy * bk2.y;  // padded key = bias (NOT masked)
    }
  }
  // ---- v rows in J^t order (per-lane J; clamp+select, no divergent loads) ----
  float vvx[KWW], vvy[KWW];
  #pragma unroll
  for (int t = 0; t < KWW; t++) {
    const int j = J ^ t;
    const int pos = s + d * j - off;
    const int posc = min(max(pos, 0), Ss - 1);
    uint32_t vw = *(const uint32_t*)(vp + (size_t)posc * Ee + 2 * lane);
    const bool ok = (pos >= 0) && (pos < Ss);
    vvx[t] = ok ? h2f_lo(vw) : bv2.x;
    vvy[t] = ok ? h2f_hi(vw) : bv2.y;
  }

  // ---- reduce-scatter: 16 vals over 64 lanes -> lane owns j = (lane>>2) ----
  {
    const bool hi = (lane & 32) != 0;
    #pragma unroll
    for (int j = 0; j < 8; j++) {
      float send = hi ? logit[j] : logit[j + 8];
      float recv = __shfl_xor(send, 32, 64);
      logit[j] = (hi ? logit[j + 8] : logit[j]) + recv;
    }
  }
  {
    const bool hi = (lane & 16) != 0;
    #pragma unroll
    for (int j = 0; j < 4; j++) {
      float send = hi ? logit[j] : logit[j + 4];
      float recv = __shfl_xor(send, 16, 64);
      logit[j] = (hi ? logit[j + 4] : logit[j]) + recv;
    }
  }
  {
    const bool hi = (lane & 8) != 0;
    #pragma unroll
    for (int j = 0; j < 2; j++) {
      float send = hi ? logit[j] : logit[j + 2];
      float recv = __shfl_xor(send, 8, 64);
      logit[j] = (hi ? logit[j + 2] : logit[j]) + recv;
    }
  }
  float own;
  {
    const bool hi = (lane & 4) != 0;
    float send = hi ? logit[0] : logit[1];
    float recv = __shfl_xor(send, 4, 64);
    own = (hi ? logit[1] : logit[0]) + recv;
  }
  own += __shfl_xor(own, 2, 64);
  own += __shfl_xor(own, 1, 64);   // own = full logit for j = J, replicated x4

  // ---- softmax over j (j lives on lane groups; bits 0,1 already uniform) ----
  float mx = own;
  mx = fmaxf(mx, __shfl_xor(mx, 4, 64));
  mx = fmaxf(mx, __shfl_xor(mx, 8, 64));
  mx = fmaxf(mx, __shfl_xor(mx, 16, 64));
  mx = fmaxf(mx, __shfl_xor(mx, 32, 64));
  float w = __expf(own - mx);
  float sum = w;
  sum += __shfl_xor(sum, 4, 64);
  sum += __shfl_xor(sum, 8, 64);
  sum += __shfl_xor(sum, 16, 64);
  sum += __shfl_xor(sum, 32, 64);
  w *= 1.0f / (sum * 11.313708498984760f);  // /Z /sqrt(E), post-softmax quirk

  // ---- allgather: g[t] = w[J^t] ----
  float g[KWW];
  g[0] = w;
  g[1] = __shfl_xor(g[0], 4, 64);
  #pragma unroll
  for (int t = 0; t < 2; t++) g[2 + t] = __shfl_xor(g[t], 8, 64);
  #pragma unroll
  for (int t = 0; t < 4; t++) g[4 + t] = __shfl_xor(g[t], 16, 64);
  #pragma unroll
  for (int t = 0; t < 8; t++) g[8 + t] = __shfl_xor(g[t], 32, 64);

  float ax = 0.f, ay = 0.f;
  #pragma unroll
  for (int t = 0; t < KWW; t++) { ax += g[t] * vvx[t]; ay += g[t] * vvy[t]; }

  // write fp16 attn as A-matrix [b*S+s][h*E+e]
  u16* op = attn + ((size_t)(b * Ss + s)) * (Hh * Ee) + h * Ee + 2 * lane;
  *(uint32_t*)op = (uint32_t)f2h(ax) | ((uint32_t)f2h(ay) << 16);
}

// ---------------- launcher ----------------
extern "C" void kernel_launch(void* const* d_in, const int* in_sizes, int n_in,
                              void* d_out, int out_size, void* d_ws, size_t ws_size,
                              hipStream_t stream) {
  (void)in_sizes; (void)n_in; (void)out_size; (void)ws_size;
  const float* x  = (const float*)d_in[0];
  const float* Wq = (const float*)d_in[1];
  const float* bq = (const float*)d_in[2];
  const float* Wk = (const float*)d_in[3];
  const float* bk = (const float*)d_in[4];
  const float* Wv = (const float*)d_in[5];
  const float* bv = (const float*)d_in[6];
  const float* Wo = (const float*)d_in[7];
  const float* bo = (const float*)d_in[8];
  const int* dil  = (const int*)d_in[9];
  float* out = (float*)d_out;

  char* ws = (char*)d_ws;
  u16* xh  = (u16*)ws;  ws += (size_t)Mm * Kk * 2;             // 8 MB  [m][d] f16
  u16* wT  = (u16*)ws;  ws += (size_t)24 * Ee * Kk * 2;        // 6 MB  [proj*8+h][e][d] f16
  u16* woT = (u16*)ws;  ws += (size_t)Kk * Dd * 2;             // 2 MB  [d][h*E+e] f16
  u16* q = (u16*)ws; ws += (size_t)Bb * Hh * Ss * Ee * 2;      // 8 MB each, f16 [bh][s][e]
  u16* k = (u16*)ws; ws += (size_t)Bb * Hh * Ss * Ee * 2;
  u16* v = (u16*)ws; ws += (size_t)Bb * Hh * Ss * Ee * 2;
  // attn (8 MB f16) aliases xh — dead after gemm_qkv (stream-ordered)
  u16* attn = xh;

  prep<<<8192, 256, 0, stream>>>(x, Wq, Wk, Wv, Wo, xh, wT, woT);
  gemm_qkv<<<dim3(Mm / 128, 1, 24), 256, 0, stream>>>(xh, wT, bq, bk, bv, q, k, v);
  attn_kernel<<<(Bb * Hh * Ss) / 4, 256, 0, stream>>>(q, k, v, bk, bv, dil, attn);
  gemm_out<<<dim3(Mm / 64, Dd / 128), 256, 0, stream>>>(attn, woT, bo, out);
}

// Round 7
// 178.894 us; speedup vs baseline: 1.0465x; 1.0131x over previous
//
#include <hip/hip_runtime.h>
#include <stdint.h>

#define Bb 2
#define Ss 2048
#define Dd 1024
#define Hh 8
#define Ee 128
#define KWW 16
#define Mm (Bb*Ss)   // 4096
#define Kk 1024      // K for both GEMMs

typedef unsigned short u16;
typedef __attribute__((ext_vector_type(8))) _Float16 f16x8;  // 8 fp16 (4 VGPRs)
typedef __attribute__((ext_vector_type(4))) float f32x4;

// fp32 -> fp16 (RTN)
__device__ __forceinline__ u16 f2h(float f) {
  union { _Float16 h; u16 u; } v; v.h = (_Float16)f; return v.u;
}
__device__ __forceinline__ float h2f(u16 u) {
  union { u16 u; _Float16 h; } v; v.u = u; return (float)v.h;
}
__device__ __forceinline__ float h2f_lo(uint32_t w) { return h2f((u16)(w & 0xFFFF)); }
__device__ __forceinline__ float h2f_hi(uint32_t w) { return h2f((u16)(w >> 16)); }

// async global->LDS, 16B per lane. LDS dst must be wave-uniform base; HW scatters lane*16B.
__device__ __forceinline__ void gll16(const void* g, void* l) {
  __builtin_amdgcn_global_load_lds((const __attribute__((address_space(1))) void*)g,
                                   (__attribute__((address_space(3))) void*)l, 16, 0, 0);
}

// ---------------- fused prep kernel ----------------
// Weights are emitted FRAGMENT-MAJOR: [kc][n][8] per panel (kc = k/8), so the
// GEMM B-operand is loaded straight from global as per-lane b128 (no LDS for B).
// blocks [0,4096): cast x f32->f16
// blocks [4096,7168): Wq/Wk/Wv [h][D][E] -> wT[z][kc][n(E)][8], z=proj*8+h
// blocks [7168,8192): Wo [h*E][D] -> woT[nb][kc][nn][8], n = nb*128+nn over D
__global__ __launch_bounds__(256) void prep(
    const float* __restrict__ x, const float* __restrict__ Wq,
    const float* __restrict__ Wk, const float* __restrict__ Wv,
    const float* __restrict__ Wo,
    u16* __restrict__ xh, u16* __restrict__ wT, u16* __restrict__ woT) {
  const int bid = blockIdx.x;
  const int tid = threadIdx.x;
  if (bid < 4096) {
    int i = (bid * 256 + tid) * 4;
    float4 f = *(const float4*)(x + i);
    uint64_t pk = (uint64_t)f2h(f.x) | ((uint64_t)f2h(f.y) << 16) |
                  ((uint64_t)f2h(f.z) << 32) | ((uint64_t)f2h(f.w) << 48);
    *(uint64_t*)(xh + i) = pk;
    return;
  }
  __shared__ float tile[32][33];  // +1 pad: bank-conflict-free
  const int tx = tid & 31, ty = tid >> 5;  // (32,8) shape
  if (bid < 4096 + 3072) {
    const int idx = bid - 4096;
    const int z = idx >> 7, rem = idx & 127;
    const int h = z & 7;
    const float* W = (z < 8) ? Wq : (z < 16) ? Wk : Wv;
    const float* ib = W + (size_t)h * Dd * Ee;
    u16* ob = wT + (size_t)z * Ee * Kk;   // 131072 elems = [kc 128][n 128][8]
    const int r0 = (rem & 31) * 32, c0 = (rem >> 5) * 32;  // r over D(=k), c over E(=n)
    #pragma unroll
    for (int kq = 0; kq < 4; kq++)
      tile[ty + 8*kq][tx] = ib[(size_t)(r0 + ty + 8*kq) * Ee + (c0 + tx)];
    __syncthreads();
    const int k = r0 + tx;
    #pragma unroll
    for (int kq = 0; kq < 4; kq++) {
      const int n = c0 + ty + 8*kq;
      ob[(((size_t)(k >> 3) * 128 + n) << 3) + (k & 7)] = f2h(tile[tx][ty + 8*kq]);
    }
  } else {
    const int idx = bid - (4096 + 3072);
    const int r0 = (idx & 31) * 32, c0 = (idx >> 5) * 32;  // r over h*E(=k), c over D(=n)
    const int C = Dd;
    #pragma unroll
    for (int kq = 0; kq < 4; kq++)
      tile[ty + 8*kq][tx] = Wo[(size_t)(r0 + ty + 8*kq) * C + (c0 + tx)];
    __syncthreads();
    const int k = r0 + tx;
    #pragma unroll
    for (int kq = 0; kq < 4; kq++) {
      const int n = c0 + ty + 8*kq;
      woT[(size_t)(n >> 7) * 131072 +
          (((size_t)(k >> 3) * 128 + (n & 127)) << 3) + (k & 7)] = f2h(tile[tx][ty + 8*kq]);
    }
  }
}

// ---------------- GEMM core: MTx128 tile, BK=64, 4 waves, 16x16x32 f16 MFMA ----------------
// A: [M][K] f16 row-major, staged via global_load_lds into XOR-swizzled LDS
//    (chunk p = row*8 + pc holds A[row][((pc ^ (row&7))*8) .. +7]; conflicts = 0, measured R5).
// B: fragment-major global [kc][n(128)][8] — loaded per-lane as b128 straight to
//    VGPRs (L2-resident, coalesced 256B per 16-lane quad), register-double-buffered
//    so B(kt+1) latency hides behind the MFMA stream. No LDS for B: halves LDS
//    traffic per block-iter (the measured ceiling of this structure).
template<int MT>   // 128 or 64
__device__ __forceinline__ void gemm_core(
    const u16* __restrict__ A, const u16* __restrict__ Btf,
    u16* As, f32x4 (&acc)[MT / 32][4]) {
  constexpr int MI = MT / 32;
  const int tid = threadIdx.x;
  const int wave = tid >> 6;
  const int lane = tid & 63;
  // lane l -> row +(l>>3), chunk col pc = l&7, logical col lc = pc ^ (l>>3)
  const size_t lnoff = (size_t)(lane >> 3) * Kk + (size_t)(((lane & 7) ^ (lane >> 3)) * 8);

  const int wm = (wave >> 1) * (MT / 2);  // wave 2x2 arrangement
  const int wn = (wave & 1) * 64;
  const int fr = lane & 15;            // A: m-in-16 / B: n-in-16
  const int q  = lane >> 4;            // k quad: holds k = kwin*32 + q*8 .. +7
  const int sw = fr & 7;               // row-swizzle for A frag reads

  // B frag pointer: elem offset ((kc*128) + n)*8, kc = kt/8 + ks*4 + q, n = wn + j*16 + fr
  const u16* bptr = Btf + ((size_t)q * 128 + wn + fr) * 8;
  f16x8 bcur[8], bnxt[8];
  #pragma unroll
  for (int ks = 0; ks < 2; ks++)
    #pragma unroll
    for (int j = 0; j < 4; j++)
      bcur[ks * 4 + j] = *(const f16x8*)(bptr + (ks * 4) * 1024 + j * 128);

  #pragma unroll
  for (int i = 0; i < MI; i++)
    #pragma unroll
    for (int j = 0; j < 4; j++)
      #pragma unroll
      for (int r = 0; r < 4; r++) acc[i][j][r] = 0.0f;

  for (int kt = 0; kt < Kk; kt += 64) {
    #pragma unroll
    for (int c = 0; c < MI; c++)
      gll16(A + lnoff + (size_t)((c * 4 + wave) * 8) * Kk + kt, As + (c * 4 + wave) * 512);
    __syncthreads();   // drains vmcnt (A staging) before LDS reads
    const int ktn = (kt + 64) & (Kk - 1);   // last-iter loads harmless (values unused)
    #pragma unroll
    for (int ks = 0; ks < 2; ks++)
      #pragma unroll
      for (int j = 0; j < 4; j++)
        bnxt[ks * 4 + j] = *(const f16x8*)(bptr + ((ktn >> 3) + ks * 4) * 1024 + j * 128);
    #pragma unroll
    for (int ks = 0; ks < 2; ks++) {
      const int col = ((ks << 2) | q) ^ sw;   // phys 16B-chunk column (A swizzle)
      f16x8 ah[MI];
      #pragma unroll
      for (int i = 0; i < MI; i++)
        ah[i] = *(const f16x8*)(As + (wm + i * 16 + fr) * 64 + col * 8);
      #pragma unroll
      for (int i = 0; i < MI; i++)
        #pragma unroll
        for (int j = 0; j < 4; j++)
          acc[i][j] = __builtin_amdgcn_mfma_f32_16x16x32_f16(ah[i], bcur[ks * 4 + j], acc[i][j], 0, 0, 0);
    }
    __syncthreads();   // ds_reads done before next staging overwrites As
    #pragma unroll
    for (int t = 0; t < 8; t++) bcur[t] = bnxt[t];
  }
}

// C/D layout (measured m89/m91): col = lane&15, row = (lane>>4)*4 + reg

__global__ __launch_bounds__(256) void gemm_qkv(
    const u16* __restrict__ xh, const u16* __restrict__ wT,
    const float* __restrict__ bq, const float* __restrict__ bk, const float* __restrict__ bv,
    u16* __restrict__ q, u16* __restrict__ k, u16* __restrict__ v) {
  __shared__ u16 As[128 * 64];
  const int m0 = blockIdx.x * 128;
  const int z = blockIdx.z;            // proj*8 + h
  const int proj = z >> 3, h = z & 7;
  f32x4 acc[4][4];
  gemm_core<128>(xh + (size_t)m0 * Kk, wT + (size_t)z * (Ee * Kk), As, acc);

  u16* dst = proj == 0 ? q : (proj == 1 ? k : v);
  const float* bias = proj == 0 ? bq : (proj == 1 ? bk : bv);
  const int wave = threadIdx.x >> 6, lane = threadIdx.x & 63;
  const int wm = (wave >> 1) * 64, wn = (wave & 1) * 64;
  const int cn = lane & 15, rq4 = (lane >> 4) * 4;
  #pragma unroll
  for (int j = 0; j < 4; j++) {
    const int e = wn + j * 16 + cn;
    const float bb = bias[h * Ee + e];
    #pragma unroll
    for (int i = 0; i < 4; i++) {
      #pragma unroll
      for (int r = 0; r < 4; r++) {
        const int m = m0 + wm + i * 16 + rq4 + r;     // m = b*S + s
        const int b = m >> 11, s = m & (Ss - 1);
        dst[(((size_t)(b * Hh + h)) * Ss + s) * Ee + e] = f2h(acc[i][j][r] + bb);
      }
    }
  }
}

__global__ __launch_bounds__(256) void gemm_out(
    const u16* __restrict__ attn, const u16* __restrict__ woT,
    const float* __restrict__ bo, float* __restrict__ out) {
  __shared__ u16 As[64 * 64];
  const int m0 = blockIdx.x * 64;
  const int n0 = blockIdx.y * 128;
  f32x4 acc[2][4];
  gemm_core<64>(attn + (size_t)m0 * Kk, woT + (size_t)blockIdx.y * 131072, As, acc);
  const int wave = threadIdx.x >> 6, lane = threadIdx.x & 63;
  const int wm = (wave >> 1) * 32, wn = (wave & 1) * 64;
  const int cn = lane & 15, rq4 = (lane >> 4) * 4;
  #pragma unroll
  for (int j = 0; j < 4; j++) {
    const int n = n0 + wn + j * 16 + cn;
    const float bb = bo[n];
    #pragma unroll
    for (int i = 0; i < 2; i++) {
      #pragma unroll
      for (int r = 0; r < 4; r++) {
        const int m = m0 + wm + i * 16 + rq4 + r;
        out[(size_t)m * Dd + n] = acc[i][j][r] + bb;
      }
    }
  }
}

// ---------------- attention: one wave per (b,h,s), fp16 loads, fp32 math ----------------
// Cross-lane plan: reduce-scatter (17 sh) -> per-lane logit j=(lane>>2) -> max/sum
// butterflies (8 sh) -> 1 exp -> allgather weights (15 sh). v rows loaded in J^t
// order so every register index is compile-time.
__global__ __launch_bounds__(256) void attn_kernel(
    const u16* __restrict__ q, const u16* __restrict__ k, const u16* __restrict__ v,
    const float* __restrict__ bk, const float* __restrict__ bv,
    const int* __restrict__ dil, u16* __restrict__ attn) {
  // XCD-contiguous swizzle: XCD i (= blockIdx%8 round-robin) gets a contiguous
  // wid range = 2 whole (b,h) panels -> disjoint ~5MB L2 working set per XCD.
  const int nblk = (Bb * Hh * Ss) / 4;           // 8192
  const int blk = (blockIdx.x & 7) * (nblk / 8) + (blockIdx.x >> 3);
  const int wid = blk * 4 + (threadIdx.x >> 6);
  const int lane = threadIdx.x & 63;
  const int s = wid & (Ss - 1);
  const int bh = wid >> 11;          // b*H + h
  const int h = bh & 7, b = bh >> 3;
  const int d = dil[h];
  const size_t base = (size_t)bh * Ss * Ee;      // u16 elements
  const u16* kp = k + base;
  const u16* vp = v + base;
  const uint32_t qw = *(const uint32_t*)(q + base + (size_t)s * Ee + 2 * lane);
  const float qx = h2f_lo(qw), qy = h2f_hi(qw);
  const float2 bk2 = ((const float2*)(bk + h * Ee))[lane];
  const float2 bv2 = ((const float2*)(bv + h * Ee))[lane];
  const int off = (d * (KWW - 1)) >> 1;
  const int J = (lane >> 2) & 15;

  // ---- logit partials (absolute j; in-window test is wave-uniform) ----
  float logit[KWW];
  #pragma unroll
  for (int j = 0; j < KWW; j++) {
    const int pos = s + d * j - off;
    if (pos >= 0 && pos < Ss) {
      uint32_t kw = *(const uint32_t*)(kp + (size_t)pos * Ee + 2 * lane);
      logit[j] = qx * h2f_lo(kw) + qy * h2f_hi(kw);
    } else {
      logit[j] = qx * bk2.x + qy * bk2.y;  // padded key = bias (NOT masked)
    }
  }
  // ---- v rows in J^t order (per-lane J; clamp+select, no divergent loads) ----
  float vvx[KWW], vvy[KWW];
  #pragma unroll
  for (int t = 0; t < KWW; t++) {
    const int j = J ^ t;
    const int pos = s + d * j - off;
    const int posc = min(max(pos, 0), Ss - 1);
    uint32_t vw = *(const uint32_t*)(vp + (size_t)posc * Ee + 2 * lane);
    const bool ok = (pos >= 0) && (pos < Ss);
    vvx[t] = ok ? h2f_lo(vw) : bv2.x;
    vvy[t] = ok ? h2f_hi(vw) : bv2.y;
  }

  // ---- reduce-scatter: 16 vals over 64 lanes -> lane owns j = (lane>>2) ----
  {
    const bool hi = (lane & 32) != 0;
    #pragma unroll
    for (int j = 0; j < 8; j++) {
      float send = hi ? logit[j] : logit[j + 8];
      float recv = __shfl_xor(send, 32, 64);
      logit[j] = (hi ? logit[j + 8] : logit[j]) + recv;
    }
  }
  {
    const bool hi = (lane & 16) != 0;
    #pragma unroll
    for (int j = 0; j < 4; j++) {
      float send = hi ? logit[j] : logit[j + 4];
      float recv = __shfl_xor(send, 16, 64);
      logit[j] = (hi ? logit[j + 4] : logit[j]) + recv;
    }
  }
  {
    const bool hi = (lane & 8) != 0;
    #pragma unroll
    for (int j = 0; j < 2; j++) {
      float send = hi ? logit[j] : logit[j + 2];
      float recv = __shfl_xor(send, 8, 64);
      logit[j] = (hi ? logit[j + 2] : logit[j]) + recv;
    }
  }
  float own;
  {
    const bool hi = (lane & 4) != 0;
    float send = hi ? logit[0] : logit[1];
    float recv = __shfl_xor(send, 4, 64);
    own = (hi ? logit[1] : logit[0]) + recv;
  }
  own += __shfl_xor(own, 2, 64);
  own += __shfl_xor(own, 1, 64);   // own = full logit for j = J, replicated x4

  // ---- softmax over j (j lives on lane groups; bits 0,1 already uniform) ----
  float mx = own;
  mx = fmaxf(mx, __shfl_xor(mx, 4, 64));
  mx = fmaxf(mx, __shfl_xor(mx, 8, 64));
  mx = fmaxf(mx, __shfl_xor(mx, 16, 64));
  mx = fmaxf(mx, __shfl_xor(mx, 32, 64));
  float w = __expf(own - mx);
  float sum = w;
  sum += __shfl_xor(sum, 4, 64);
  sum += __shfl_xor(sum, 8, 64);
  sum += __shfl_xor(sum, 16, 64);
  sum += __shfl_xor(sum, 32, 64);
  w *= 1.0f / (sum * 11.313708498984760f);  // /Z /sqrt(E), post-softmax quirk

  // ---- allgather: g[t] = w[J^t] ----
  float g[KWW];
  g[0] = w;
  g[1] = __shfl_xor(g[0], 4, 64);
  #pragma unroll
  for (int t = 0; t < 2; t++) g[2 + t] = __shfl_xor(g[t], 8, 64);
  #pragma unroll
  for (int t = 0; t < 4; t++) g[4 + t] = __shfl_xor(g[t], 16, 64);
  #pragma unroll
  for (int t = 0; t < 8; t++) g[8 + t] = __shfl_xor(g[t], 32, 64);

  float ax = 0.f, ay = 0.f;
  #pragma unroll
  for (int t = 0; t < KWW; t++) { ax += g[t] * vvx[t]; ay += g[t] * vvy[t]; }

  // write fp16 attn as A-matrix [b*S+s][h*E+e]
  u16* op = attn + ((size_t)(b * Ss + s)) * (Hh * Ee) + h * Ee + 2 * lane;
  *(uint32_t*)op = (uint32_t)f2h(ax) | ((uint32_t)f2h(ay) << 16);
}

// ---------------- launcher ----------------
extern "C" void kernel_launch(void* const* d_in, const int* in_sizes, int n_in,
                              void* d_out, int out_size, void* d_ws, size_t ws_size,
                              hipStream_t stream) {
  (void)in_sizes; (void)n_in; (void)out_size; (void)ws_size;
  const float* x  = (const float*)d_in[0];
  const float* Wq = (const float*)d_in[1];
  const float* bq = (const float*)d_in[2];
  const float* Wk = (const float*)d_in[3];
  const float* bk = (const float*)d_in[4];
  const float* Wv = (const float*)d_in[5];
  const float* bv = (const float*)d_in[6];
  const float* Wo = (const float*)d_in[7];
  const float* bo = (const float*)d_in[8];
  const int* dil  = (const int*)d_in[9];
  float* out = (float*)d_out;

  char* ws = (char*)d_ws;
  u16* xh  = (u16*)ws;  ws += (size_t)Mm * Kk * 2;             // 8 MB  [m][d] f16
  u16* wT  = (u16*)ws;  ws += (size_t)24 * Ee * Kk * 2;        // 6 MB  frag-major [z][kc][n][8]
  u16* woT = (u16*)ws;  ws += (size_t)Kk * Dd * 2;             // 2 MB  frag-major [nb][kc][nn][8]
  u16* q = (u16*)ws; ws += (size_t)Bb * Hh * Ss * Ee * 2;      // 8 MB each, f16 [bh][s][e]
  u16* k = (u16*)ws; ws += (size_t)Bb * Hh * Ss * Ee * 2;
  u16* v = (u16*)ws; ws += (size_t)Bb * Hh * Ss * Ee * 2;
  // attn (8 MB f16) aliases xh — dead after gemm_qkv (stream-ordered)
  u16* attn = xh;

  prep<<<8192, 256, 0, stream>>>(x, Wq, Wk, Wv, Wo, xh, wT, woT);
  gemm_qkv<<<dim3(Mm / 128, 1, 24), 256, 0, stream>>>(xh, wT, bq, bk, bv, q, k, v);
  attn_kernel<<<(Bb * Hh * Ss) / 4, 256, 0, stream>>>(q, k, v, bk, bv, dil, attn);
  gemm_out<<<dim3(Mm / 64, Dd / 128), 256, 0, stream>>>(attn, woT, bo, out);
}

// Round 8
// 173.798 us; speedup vs baseline: 1.0772x; 1.0293x over previous
//
#include <hip/hip_runtime.h>
#include <stdint.h>

#define Bb 2
#define Ss 2048
#define Dd 1024
#define Hh 8
#define Ee 128
#define KWW 16
#define Mm (Bb*Ss)   // 4096
#define Kk 1024      // K for both GEMMs

typedef unsigned short u16;
typedef __attribute__((ext_vector_type(8))) _Float16 f16x8;  // 8 fp16 (4 VGPRs)
typedef __attribute__((ext_vector_type(4))) float f32x4;

// fp32 -> fp16 (RTN)
__device__ __forceinline__ u16 f2h(float f) {
  union { _Float16 h; u16 u; } v; v.h = (_Float16)f; return v.u;
}
__device__ __forceinline__ float h2f(u16 u) {
  union { u16 u; _Float16 h; } v; v.u = u; return (float)v.h;
}
__device__ __forceinline__ float h2f_lo(uint32_t w) { return h2f((u16)(w & 0xFFFF)); }
__device__ __forceinline__ float h2f_hi(uint32_t w) { return h2f((u16)(w >> 16)); }

// async global->LDS, 16B per lane. LDS dst must be wave-uniform base; HW scatters lane*16B.
__device__ __forceinline__ void gll16(const void* g, void* l) {
  __builtin_amdgcn_global_load_lds((const __attribute__((address_space(1))) void*)g,
                                   (__attribute__((address_space(3))) void*)l, 16, 0, 0);
}

// ---------------- fused prep kernel ----------------
// Weights are emitted FRAGMENT-MAJOR: [kc][n][8] per panel (kc = k/8), so the
// GEMM B-operand is loaded straight from global as per-lane b128 (no LDS for B).
// blocks [0,4096): cast x f32->f16
// blocks [4096,7168): Wq/Wk/Wv [h][D][E] -> wT[z][kc][n(E)][8], z=proj*8+h
// blocks [7168,8192): Wo [h*E][D] -> woT[nb][kc][nn][8], n = nb*128+nn over D
__global__ __launch_bounds__(256) void prep(
    const float* __restrict__ x, const float* __restrict__ Wq,
    const float* __restrict__ Wk, const float* __restrict__ Wv,
    const float* __restrict__ Wo,
    u16* __restrict__ xh, u16* __restrict__ wT, u16* __restrict__ woT) {
  const int bid = blockIdx.x;
  const int tid = threadIdx.x;
  if (bid < 4096) {
    int i = (bid * 256 + tid) * 4;
    float4 f = *(const float4*)(x + i);
    uint64_t pk = (uint64_t)f2h(f.x) | ((uint64_t)f2h(f.y) << 16) |
                  ((uint64_t)f2h(f.z) << 32) | ((uint64_t)f2h(f.w) << 48);
    *(uint64_t*)(xh + i) = pk;
    return;
  }
  __shared__ float tile[32][33];  // +1 pad: bank-conflict-free
  const int tx = tid & 31, ty = tid >> 5;  // (32,8) shape
  if (bid < 4096 + 3072) {
    const int idx = bid - 4096;
    const int z = idx >> 7, rem = idx & 127;
    const int h = z & 7;
    const float* W = (z < 8) ? Wq : (z < 16) ? Wk : Wv;
    const float* ib = W + (size_t)h * Dd * Ee;
    u16* ob = wT + (size_t)z * Ee * Kk;   // 131072 elems = [kc 128][n 128][8]
    const int r0 = (rem & 31) * 32, c0 = (rem >> 5) * 32;  // r over D(=k), c over E(=n)
    #pragma unroll
    for (int kq = 0; kq < 4; kq++)
      tile[ty + 8*kq][tx] = ib[(size_t)(r0 + ty + 8*kq) * Ee + (c0 + tx)];
    __syncthreads();
    const int k = r0 + tx;
    #pragma unroll
    for (int kq = 0; kq < 4; kq++) {
      const int n = c0 + ty + 8*kq;
      ob[(((size_t)(k >> 3) * 128 + n) << 3) + (k & 7)] = f2h(tile[tx][ty + 8*kq]);
    }
  } else {
    const int idx = bid - (4096 + 3072);
    const int r0 = (idx & 31) * 32, c0 = (idx >> 5) * 32;  // r over h*E(=k), c over D(=n)
    const int C = Dd;
    #pragma unroll
    for (int kq = 0; kq < 4; kq++)
      tile[ty + 8*kq][tx] = Wo[(size_t)(r0 + ty + 8*kq) * C + (c0 + tx)];
    __syncthreads();
    const int k = r0 + tx;
    #pragma unroll
    for (int kq = 0; kq < 4; kq++) {
      const int n = c0 + ty + 8*kq;
      woT[(size_t)(n >> 7) * 131072 +
          (((size_t)(k >> 3) * 128 + (n & 127)) << 3) + (k & 7)] = f2h(tile[tx][ty + 8*kq]);
    }
  }
}

// ---------------- GEMM core: MTx128 tile, BK=64, 4 waves, 16x16x32 f16 MFMA ----------------
// A: [M][K] f16 row-major -> global_load_lds into XOR-swizzled LDS, DOUBLE-BUFFERED:
//    stage A(w+1) into buf^1 while MFMAs consume buf^0; ONE barrier per iteration,
//    so the vmcnt(0) drain at the barrier covers loads that had a full compute
//    phase to land (R7: exposed staging latency was the 2400cyc/iter critical path).
//    Swizzle: chunk p = row*8 + pc holds A[row][((pc ^ (row&7))*8) .. +7] (conflicts=0, R5).
// B: fragment-major global [kc][n(128)][8] — per-lane b128 loads straight to VGPRs
//    (L2-resident), register-double-buffered one iteration ahead.
// As points to 2*MT*64 u16 of LDS (two buffers).
template<int MT>   // 128 or 64
__device__ __forceinline__ void gemm_core(
    const u16* __restrict__ A, const u16* __restrict__ Btf,
    u16* As, f32x4 (&acc)[MT / 32][4]) {
  constexpr int MI = MT / 32;
  const int tid = threadIdx.x;
  const int wave = tid >> 6;
  const int lane = tid & 63;
  // lane l -> row +(l>>3), chunk col pc = l&7, logical col lc = pc ^ (l>>3)
  const size_t lnoff = (size_t)(lane >> 3) * Kk + (size_t)(((lane & 7) ^ (lane >> 3)) * 8);

  const int wm = (wave >> 1) * (MT / 2);  // wave 2x2 arrangement
  const int wn = (wave & 1) * 64;
  const int fr = lane & 15;            // A: m-in-16 / B: n-in-16
  const int q  = lane >> 4;            // k quad: holds k = kwin*32 + q*8 .. +7
  const int sw = fr & 7;               // row-swizzle for A frag reads

  // B frag pointer: elem offset kc*1024 + n*8, kc = kt/8 + ks*4 + q (q folded in)
  const u16* bptr = Btf + ((size_t)q * 128 + wn + fr) * 8;
  f16x8 bcur[8], bnxt[8];
  #pragma unroll
  for (int ks = 0; ks < 2; ks++)
    #pragma unroll
    for (int j = 0; j < 4; j++)
      bcur[ks * 4 + j] = *(const f16x8*)(bptr + (ks * 4) * 1024 + j * 128);

  #pragma unroll
  for (int i = 0; i < MI; i++)
    #pragma unroll
    for (int j = 0; j < 4; j++)
      #pragma unroll
      for (int r = 0; r < 4; r++) acc[i][j][r] = 0.0f;

  // prologue: stage window 0 into buf0 (latency exposed once)
  #pragma unroll
  for (int c = 0; c < MI; c++)
    gll16(A + lnoff + (size_t)((c * 4 + wave) * 8) * Kk, As + (c * 4 + wave) * 512);
  __syncthreads();

  for (int w = 0; w < Kk / 64; w++) {
    const int kt = w * 64;
    u16* cur = As + (w & 1) * (MT * 64);
    u16* nxt = As + ((w + 1) & 1) * (MT * 64);
    // stage next A window (overlaps with compute below; drained at loop-end barrier)
    if (w + 1 < Kk / 64) {
      #pragma unroll
      for (int c = 0; c < MI; c++)
        gll16(A + lnoff + (size_t)((c * 4 + wave) * 8) * Kk + kt + 64, nxt + (c * 4 + wave) * 512);
    }
    // prefetch next B window into regs (wrap on last iter; values unused)
    const int ktn = (kt + 64) & (Kk - 1);
    #pragma unroll
    for (int ks = 0; ks < 2; ks++)
      #pragma unroll
      for (int j = 0; j < 4; j++)
        bnxt[ks * 4 + j] = *(const f16x8*)(bptr + ((ktn >> 3) + ks * 4) * 1024 + j * 128);
    // compute current window
    #pragma unroll
    for (int ks = 0; ks < 2; ks++) {
      const int col = ((ks << 2) | q) ^ sw;   // phys 16B-chunk column (A swizzle)
      f16x8 ah[MI];
      #pragma unroll
      for (int i = 0; i < MI; i++)
        ah[i] = *(const f16x8*)(cur + (wm + i * 16 + fr) * 64 + col * 8);
      #pragma unroll
      for (int i = 0; i < MI; i++)
        #pragma unroll
        for (int j = 0; j < 4; j++)
          acc[i][j] = __builtin_amdgcn_mfma_f32_16x16x32_f16(ah[i], bcur[ks * 4 + j], acc[i][j], 0, 0, 0);
    }
    __syncthreads();   // single barrier: my ds_reads of cur done; all waves' stage of nxt drained
    #pragma unroll
    for (int t = 0; t < 8; t++) bcur[t] = bnxt[t];
  }
}

// C/D layout (measured m89/m91): col = lane&15, row = (lane>>4)*4 + reg

__global__ __launch_bounds__(256) void gemm_qkv(
    const u16* __restrict__ xh, const u16* __restrict__ wT,
    const float* __restrict__ bq, const float* __restrict__ bk, const float* __restrict__ bv,
    u16* __restrict__ q, u16* __restrict__ k, u16* __restrict__ v) {
  __shared__ u16 As[128 * 64 * 2];
  const int m0 = blockIdx.x * 128;
  const int z = blockIdx.z;            // proj*8 + h
  const int proj = z >> 3, h = z & 7;
  f32x4 acc[4][4];
  gemm_core<128>(xh + (size_t)m0 * Kk, wT + (size_t)z * (Ee * Kk), As, acc);

  u16* dst = proj == 0 ? q : (proj == 1 ? k : v);
  const float* bias = proj == 0 ? bq : (proj == 1 ? bk : bv);
  const int wave = threadIdx.x >> 6, lane = threadIdx.x & 63;
  const int wm = (wave >> 1) * 64, wn = (wave & 1) * 64;
  const int cn = lane & 15, rq4 = (lane >> 4) * 4;
  #pragma unroll
  for (int j = 0; j < 4; j++) {
    const int e = wn + j * 16 + cn;
    const float bb = bias[h * Ee + e];
    #pragma unroll
    for (int i = 0; i < 4; i++) {
      #pragma unroll
      for (int r = 0; r < 4; r++) {
        const int m = m0 + wm + i * 16 + rq4 + r;     // m = b*S + s
        const int b = m >> 11, s = m & (Ss - 1);
        dst[(((size_t)(b * Hh + h)) * Ss + s) * Ee + e] = f2h(acc[i][j][r] + bb);
      }
    }
  }
}

__global__ __launch_bounds__(256) void gemm_out(
    const u16* __restrict__ attn, const u16* __restrict__ woT,
    const float* __restrict__ bo, float* __restrict__ out) {
  __shared__ u16 As[64 * 64 * 2];
  const int m0 = blockIdx.x * 64;
  const int n0 = blockIdx.y * 128;
  f32x4 acc[2][4];
  gemm_core<64>(attn + (size_t)m0 * Kk, woT + (size_t)blockIdx.y * 131072, As, acc);
  const int wave = threadIdx.x >> 6, lane = threadIdx.x & 63;
  const int wm = (wave >> 1) * 32, wn = (wave & 1) * 64;
  const int cn = lane & 15, rq4 = (lane >> 4) * 4;
  #pragma unroll
  for (int j = 0; j < 4; j++) {
    const int n = n0 + wn + j * 16 + cn;
    const float bb = bo[n];
    #pragma unroll
    for (int i = 0; i < 2; i++) {
      #pragma unroll
      for (int r = 0; r < 4; r++) {
        const int m = m0 + wm + i * 16 + rq4 + r;
        out[(size_t)m * Dd + n] = acc[i][j][r] + bb;
      }
    }
  }
}

// ---------------- attention: one wave per (b,h,s), fp16 loads, fp32 math ----------------
// Cross-lane plan: reduce-scatter (17 sh) -> per-lane logit j=(lane>>2) -> max/sum
// butterflies (8 sh) -> 1 exp -> allgather weights (15 sh). v rows loaded in J^t
// order so every register index is compile-time.
__global__ __launch_bounds__(256) void attn_kernel(
    const u16* __restrict__ q, const u16* __restrict__ k, const u16* __restrict__ v,
    const float* __restrict__ bk, const float* __restrict__ bv,
    const int* __restrict__ dil, u16* __restrict__ attn) {
  // XCD-contiguous swizzle: XCD i (= blockIdx%8 round-robin) gets a contiguous
  // wid range = 2 whole (b,h) panels -> disjoint ~5MB L2 working set per XCD.
  const int nblk = (Bb * Hh * Ss) / 4;           // 8192
  const int blk = (blockIdx.x & 7) * (nblk / 8) + (blockIdx.x >> 3);
  const int wid = blk * 4 + (threadIdx.x >> 6);
  const int lane = threadIdx.x & 63;
  const int s = wid & (Ss - 1);
  const int bh = wid >> 11;          // b*H + h
  const int h = bh & 7, b = bh >> 3;
  const int d = dil[h];
  const size_t base = (size_t)bh * Ss * Ee;      // u16 elements
  const u16* kp = k + base;
  const u16* vp = v + base;
  const uint32_t qw = *(const uint32_t*)(q + base + (size_t)s * Ee + 2 * lane);
  const float qx = h2f_lo(qw), qy = h2f_hi(qw);
  const float2 bk2 = ((const float2*)(bk + h * Ee))[lane];
  const float2 bv2 = ((const float2*)(bv + h * Ee))[lane];
  const int off = (d * (KWW - 1)) >> 1;
  const int J = (lane >> 2) & 15;

  // ---- logit partials (absolute j; in-window test is wave-uniform) ----
  float logit[KWW];
  #pragma unroll
  for (int j = 0; j < KWW; j++) {
    const int pos = s + d * j - off;
    if (pos >= 0 && pos < Ss) {
      uint32_t kw = *(const uint32_t*)(kp + (size_t)pos * Ee + 2 * lane);
      logit[j] = qx * h2f_lo(kw) + qy * h2f_hi(kw);
    } else {
      logit[j] = qx * bk2.x + qy * bk2.y;  // padded key = bias (NOT masked)
    }
  }
  // ---- v rows in J^t order (per-lane J; clamp+select, no divergent loads) ----
  float vvx[KWW], vvy[KWW];
  #pragma unroll
  for (int t = 0; t < KWW; t++) {
    const int j = J ^ t;
    const int pos = s + d * j - off;
    const int posc = min(max(pos, 0), Ss - 1);
    uint32_t vw = *(const uint32_t*)(vp + (size_t)posc * Ee + 2 * lane);
    const bool ok = (pos >= 0) && (pos < Ss);
    vvx[t] = ok ? h2f_lo(vw) : bv2.x;
    vvy[t] = ok ? h2f_hi(vw) : bv2.y;
  }

  // ---- reduce-scatter: 16 vals over 64 lanes -> lane owns j = (lane>>2) ----
  {
    const bool hi = (lane & 32) != 0;
    #pragma unroll
    for (int j = 0; j < 8; j++) {
      float send = hi ? logit[j] : logit[j + 8];
      float recv = __shfl_xor(send, 32, 64);
      logit[j] = (hi ? logit[j + 8] : logit[j]) + recv;
    }
  }
  {
    const bool hi = (lane & 16) != 0;
    #pragma unroll
    for (int j = 0; j < 4; j++) {
      float send = hi ? logit[j] : logit[j + 4];
      float recv = __shfl_xor(send, 16, 64);
      logit[j] = (hi ? logit[j + 4] : logit[j]) + recv;
    }
  }
  {
    const bool hi = (lane & 8) != 0;
    #pragma unroll
    for (int j = 0; j < 2; j++) {
      float send = hi ? logit[j] : logit[j + 2];
      float recv = __shfl_xor(send, 8, 64);
      logit[j] = (hi ? logit[j + 2] : logit[j]) + recv;
    }
  }
  float own;
  {
    const bool hi = (lane & 4) != 0;
    float send = hi ? logit[0] : logit[1];
    float recv = __shfl_xor(send, 4, 64);
    own = (hi ? logit[1] : logit[0]) + recv;
  }
  own += __shfl_xor(own, 2, 64);
  own += __shfl_xor(own, 1, 64);   // own = full logit for j = J, replicated x4

  // ---- softmax over j (j lives on lane groups; bits 0,1 already uniform) ----
  float mx = own;
  mx = fmaxf(mx, __shfl_xor(mx, 4, 64));
  mx = fmaxf(mx, __shfl_xor(mx, 8, 64));
  mx = fmaxf(mx, __shfl_xor(mx, 16, 64));
  mx = fmaxf(mx, __shfl_xor(mx, 32, 64));
  float w = __expf(own - mx);
  float sum = w;
  sum += __shfl_xor(sum, 4, 64);
  sum += __shfl_xor(sum, 8, 64);
  sum += __shfl_xor(sum, 16, 64);
  sum += __shfl_xor(sum, 32, 64);
  w *= 1.0f / (sum * 11.313708498984760f);  // /Z /sqrt(E), post-softmax quirk

  // ---- allgather: g[t] = w[J^t] ----
  float g[KWW];
  g[0] = w;
  g[1] = __shfl_xor(g[0], 4, 64);
  #pragma unroll
  for (int t = 0; t < 2; t++) g[2 + t] = __shfl_xor(g[t], 8, 64);
  #pragma unroll
  for (int t = 0; t < 4; t++) g[4 + t] = __shfl_xor(g[t], 16, 64);
  #pragma unroll
  for (int t = 0; t < 8; t++) g[8 + t] = __shfl_xor(g[t], 32, 64);

  float ax = 0.f, ay = 0.f;
  #pragma unroll
  for (int t = 0; t < KWW; t++) { ax += g[t] * vvx[t]; ay += g[t] * vvy[t]; }

  // write fp16 attn as A-matrix [b*S+s][h*E+e]
  u16* op = attn + ((size_t)(b * Ss + s)) * (Hh * Ee) + h * Ee + 2 * lane;
  *(uint32_t*)op = (uint32_t)f2h(ax) | ((uint32_t)f2h(ay) << 16);
}

// ---------------- launcher ----------------
extern "C" void kernel_launch(void* const* d_in, const int* in_sizes, int n_in,
                              void* d_out, int out_size, void* d_ws, size_t ws_size,
                              hipStream_t stream) {
  (void)in_sizes; (void)n_in; (void)out_size; (void)ws_size;
  const float* x  = (const float*)d_in[0];
  const float* Wq = (const float*)d_in[1];
  const float* bq = (const float*)d_in[2];
  const float* Wk = (const float*)d_in[3];
  const float* bk = (const float*)d_in[4];
  const float* Wv = (const float*)d_in[5];
  const float* bv = (const float*)d_in[6];
  const float* Wo = (const float*)d_in[7];
  const float* bo = (const float*)d_in[8];
  const int* dil  = (const int*)d_in[9];
  float* out = (float*)d_out;

  char* ws = (char*)d_ws;
  u16* xh  = (u16*)ws;  ws += (size_t)Mm * Kk * 2;             // 8 MB  [m][d] f16
  u16* wT  = (u16*)ws;  ws += (size_t)24 * Ee * Kk * 2;        // 6 MB  frag-major [z][kc][n][8]
  u16* woT = (u16*)ws;  ws += (size_t)Kk * Dd * 2;             // 2 MB  frag-major [nb][kc][nn][8]
  u16* q = (u16*)ws; ws += (size_t)Bb * Hh * Ss * Ee * 2;      // 8 MB each, f16 [bh][s][e]
  u16* k = (u16*)ws; ws += (size_t)Bb * Hh * Ss * Ee * 2;
  u16* v = (u16*)ws; ws += (size_t)Bb * Hh * Ss * Ee * 2;
  // attn (8 MB f16) aliases xh — dead after gemm_qkv (stream-ordered)
  u16* attn = xh;

  prep<<<8192, 256, 0, stream>>>(x, Wq, Wk, Wv, Wo, xh, wT, woT);
  gemm_qkv<<<dim3(Mm / 128, 1, 24), 256, 0, stream>>>(xh, wT, bq, bk, bv, q, k, v);
  attn_kernel<<<(Bb * Hh * Ss) / 4, 256, 0, stream>>>(q, k, v, bk, bv, dil, attn);
  gemm_out<<<dim3(Mm / 64, Dd / 128), 256, 0, stream>>>(attn, woT, bo, out);
}